// Round 5
// baseline (689.109 us; speedup 1.0000x reference)
//
#include <hip/hip_runtime.h>
#include <hip/hip_bf16.h>
#include <math.h>

// Problem dims
#define B_SZ 32
#define S_SZ 512
#define C_SZ 512
#define E_SZ 256
#define H_SZ 8
#define D_SZ 32
#define L_SZ 4
#define N_TOK (B_SZ * S_SZ)   // 16384
#define HID 768               // 3*E
#define MB (1048576)

typedef __attribute__((ext_vector_type(8))) short bf16x8;
typedef __attribute__((ext_vector_type(4))) float f32x4_t;

__device__ __forceinline__ float gelu_f(float x) {
    return 0.5f * x * (1.0f + erff(x * 0.70710678118654752f));
}

__device__ __forceinline__ ushort f2bf(float f) {
    uint u = __float_as_uint(f);
    return (ushort)((u + 0x7FFFu + ((u >> 16) & 1u)) >> 16);
}
// RTNE pair-convert; lowers to v_cvt_pk_bf16_f32 on gfx950
__device__ __forceinline__ uint pack2(float a, float b) {
    __hip_bfloat162 h = __float22bfloat162_rn(make_float2(a, b));
    union { __hip_bfloat162 h; uint u; } c; c.h = h;
    return c.u;
}
__device__ __forceinline__ void unpack8(uint4 u, float* f) {
    f[0] = __uint_as_float((u.x & 0xFFFFu) << 16); f[1] = __uint_as_float(u.x & 0xFFFF0000u);
    f[2] = __uint_as_float((u.y & 0xFFFFu) << 16); f[3] = __uint_as_float(u.y & 0xFFFF0000u);
    f[4] = __uint_as_float((u.z & 0xFFFFu) << 16); f[5] = __uint_as_float(u.z & 0xFFFF0000u);
    f[6] = __uint_as_float((u.w & 0xFFFFu) << 16); f[7] = __uint_as_float(u.w & 0xFFFF0000u);
}

// async global->LDS, 16B per lane; LDS dest = wave-uniform base + lane*16
__device__ __forceinline__ void gload16(const ushort* g, ushort* l) {
    __builtin_amdgcn_global_load_lds(
        (const __attribute__((address_space(1))) void*)g,
        (__attribute__((address_space(3))) void*)l, 16, 0, 0);
}

// ---------------------------------------------------------------------------
// fp32 -> bf16 conversion (n % 2048 == 0, grid = n/2048)
// ---------------------------------------------------------------------------
__global__ __launch_bounds__(256)
void cvt_kernel(const float* __restrict__ src, ushort* __restrict__ dst)
{
    const int i = (blockIdx.x * 256 + threadIdx.x) * 8;
    const float4 a = *(const float4*)(src + i);
    const float4 b = *(const float4*)(src + i + 4);
    uint4 o;
    o.x = pack2(a.x, a.y); o.y = pack2(a.z, a.w);
    o.z = pack2(b.x, b.y); o.w = pack2(b.z, b.w);
    *(uint4*)(dst + i) = o;
}

// merged Wq/Wk/Wv conversion -> wqkv[L][3][256][256]; grid 384 x 256
__global__ __launch_bounds__(256)
void wqkv_cvt_kernel(const float* __restrict__ Wq, const float* __restrict__ Wk,
                     const float* __restrict__ Wv, ushort* __restrict__ dst)
{
    const int i = (blockIdx.x * 256 + threadIdx.x) * 8;   // < 786432
    const int layer = i / 196608;
    const int rem = i - layer * 196608;
    const int sub = rem >> 16, off = rem & 65535;
    const float* src = (sub == 0 ? Wq : sub == 1 ? Wk : Wv) + layer * 65536 + off;
    const float4 a = *(const float4*)src;
    const float4 b = *(const float4*)(src + 4);
    uint4 o;
    o.x = pack2(a.x, a.y); o.y = pack2(a.z, a.w);
    o.z = pack2(b.x, b.y); o.w = pack2(b.z, b.w);
    *(uint4*)(dst + i) = o;
}

// concat per-layer q/k/v biases -> bqkv[L][768]; grid 12 x 256
__global__ __launch_bounds__(256)
void bqkv_kernel(const float* __restrict__ bq, const float* __restrict__ bk,
                 const float* __restrict__ bv, float* __restrict__ dst)
{
    const int idx = blockIdx.x * 256 + threadIdx.x;   // 0..3071
    const int layer = idx / 768, j = idx % 768;
    float v = (j < 256) ? bq[layer * 256 + j]
            : (j < 512) ? bk[layer * 256 + j - 256]
                        : bv[layer * 256 + j - 512];
    dst[layer * 768 + j] = v;
}

// ---------------------------------------------------------------------------
// bf16 MFMA GEMM: C[M,F] = A[M,K](bf16) @ W[F,K](bf16)^T + bias (+bias2), ACT
// Tile 128x64, BK=32, 4 waves (2x2). Staging via global_load_lds (16B/lane)
// into double-buffered linear LDS [rows][32]; k-seg XOR-swizzled on the
// global SOURCE (seg ^= (row>>1)&3) and on the ds_read side -> 2-way (free)
// bank pattern. One barrier per K-step; next tile's DMA overlaps compute.
// EPI=1: fused QKV split (q|k -> Cb [N][512], v -> Cb2 [b][h][32][512]).
// ---------------------------------------------------------------------------
template<int ACT, int EPI, bool OF, bool OB>
__global__ __launch_bounds__(256)
void gemm_bf16_kernel(const ushort* __restrict__ A, const ushort* __restrict__ W,
                      const float* __restrict__ bias, const float* __restrict__ bias2,
                      float* __restrict__ Cf, ushort* __restrict__ Cb,
                      ushort* __restrict__ Cb2, int M, int K, int F)
{
    __shared__ __align__(16) ushort As[2][128 * 32];
    __shared__ __align__(16) ushort Bs[2][64 * 32];
    const int tid = threadIdx.x;
    const int bm = blockIdx.x * 128, bn = blockIdx.y * 64;
    const int lane = tid & 63, w = tid >> 6;
    const int lr = lane >> 2, ls = lane & 3;          // staging row-in-chunk, seg
    const int lsx = ls ^ ((lr >> 1) & 3);             // source-side swizzle
    const int wm = w >> 1, wn = w & 1;
    const int fr = lane & 15, fk = lane >> 4;
    const int rseg = (fk ^ ((fr >> 1) & 3)) * 8;      // read-side swizzle (ushort)
    f32x4_t acc[4][2] = {};

    const ushort* Ag0 = A + (size_t)(bm + w * 32 + lr) * K + lsx * 8;
    const ushort* Ag1 = Ag0 + (size_t)16 * K;
    const ushort* Wg  = W + (size_t)(bn + w * 16 + lr) * K + lsx * 8;
    const int la0 = (w * 32) * 32, la1 = (w * 32 + 16) * 32, lb = (w * 16) * 32;

    // prologue: stage tile 0 into buf 0
    gload16(Ag0, &As[0][la0]);
    gload16(Ag1, &As[0][la1]);
    gload16(Wg,  &Bs[0][lb]);
    __syncthreads();                                   // drains vmcnt

    const int NT = K >> 5;
    int cur = 0;
    for (int t = 0; t < NT; ++t) {
        if (t + 1 < NT) {                              // stage next into cur^1
            const int k0 = (t + 1) << 5;
            gload16(Ag0 + k0, &As[cur ^ 1][la0]);
            gload16(Ag1 + k0, &As[cur ^ 1][la1]);
            gload16(Wg  + k0, &Bs[cur ^ 1][lb]);
        }
        bf16x8 af[4], bw[2];
        #pragma unroll
        for (int i = 0; i < 4; ++i)
            af[i] = *(const bf16x8*)&As[cur][(wm * 64 + i * 16 + fr) * 32 + rseg];
        #pragma unroll
        for (int j = 0; j < 2; ++j)
            bw[j] = *(const bf16x8*)&Bs[cur][(wn * 32 + j * 16 + fr) * 32 + rseg];
        #pragma unroll
        for (int i = 0; i < 4; ++i)
            #pragma unroll
            for (int j = 0; j < 2; ++j)
                acc[i][j] = __builtin_amdgcn_mfma_f32_16x16x32_bf16(af[i], bw[j], acc[i][j], 0, 0, 0);
        __syncthreads();                               // drains this iter's DMA
        cur ^= 1;
    }

    // C/D layout: col = lane&15, row = (lane>>4)*4 + reg.
    #pragma unroll
    for (int j = 0; j < 2; ++j) {
        const int col = bn + wn * 32 + j * 16 + fr;
        float bb = bias[col];
        if (bias2) bb += bias2[col];
        #pragma unroll
        for (int i = 0; i < 4; ++i) {
            #pragma unroll
            for (int r = 0; r < 4; ++r) {
                const int row = bm + wm * 64 + i * 16 + fk * 4 + r;
                float t = acc[i][j][r] + bb;
                if (ACT == 1) t = gelu_f(t);
                if (ACT == 2) t = fmaxf(t, 0.0f);
                if (EPI == 1) {
                    const int b2 = row >> 9, s2 = row & 511;
                    if (col < 512) {
                        Cb[(size_t)row * 512 + col] = f2bf(t);
                    } else {
                        const int cc = col - 512;
                        Cb2[(size_t)(((b2 << 3) + (cc >> 5)) << 14) + ((cc & 31) << 9) + s2] = f2bf(t);
                    }
                } else {
                    if (OF) Cf[(size_t)row * F + col] = t;
                    if (OB) Cb[(size_t)row * F + col] = f2bf(t);
                }
            }
        }
    }
}

// ---------------------------------------------------------------------------
// MFMA flash attention. Grid (B*H, S/64). Block 256 = 4 waves; wave owns 16 q.
// qk: [N][512] bf16 (q cols 0..255, k cols 256..511, head h at h*32).
// vt: [b][h][32][512] bf16 (V transposed). out: [N][256] bf16.
// Swapped QK^T + permuted K rows -> P frags land in PV B-operand layout with
// zero shuffles. Reg-prefetch of next K/V tile overlaps compute (T14);
// setprio(1) around MFMA clusters (T5).
// ---------------------------------------------------------------------------
__global__ __launch_bounds__(256)
void attn_v3(const ushort* __restrict__ qk, const ushort* __restrict__ vt,
             ushort* __restrict__ out)
{
    __shared__ __align__(16) ushort Ks[128 * 40];
    __shared__ __align__(16) ushort Vs[32 * 168];
    const int bh = blockIdx.x, qc = blockIdx.y;
    const int b = bh >> 3, h = bh & 7;
    const int tid = threadIdx.x;
    const int w = tid >> 6, lane = tid & 63;
    const int g = lane >> 4, c = lane & 15;
    const size_t qrow = (size_t)b * 512 + qc * 64 + w * 16;

    // load + pre-scale this wave's Q fragment: lane holds Q[q=c][d=g*8..g*8+7]
    bf16x8 qf;
    {
        const uint4 qv = *(const uint4*)(qk + (qrow + c) * 512 + h * 32 + g * 8);
        float f[8]; unpack8(qv, f);
        const float scale = 0.17677669529663689f;
        union { uint u[4]; bf16x8 v; } qq;
        #pragma unroll
        for (int j = 0; j < 4; ++j) qq.u[j] = pack2(f[2*j] * scale, f[2*j+1] * scale);
        qf = qq.v;
    }

    // prefetch tile 0 into regs
    uint4 pk[2], pv[2];
    #pragma unroll
    for (int i = 0; i < 2; ++i) {
        const int idx = tid + i * 256;
        pk[i] = *(const uint4*)(qk + ((size_t)b * 512 + (idx >> 2)) * 512
                                + 256 + h * 32 + (idx & 3) * 8);
        pv[i] = *(const uint4*)(vt + (size_t)bh * 16384 + (idx >> 4) * 512 + (idx & 15) * 8);
    }

    float m = -INFINITY, l = 0.f;
    f32x4_t o0 = {0.f, 0.f, 0.f, 0.f}, o1 = {0.f, 0.f, 0.f, 0.f};
    const f32x4_t zz = {0.f, 0.f, 0.f, 0.f};

    for (int kt = 0; kt < 4; ++kt) {
        __syncthreads();
        // write staged regs -> LDS (K rows permuted within each 32-block)
        #pragma unroll
        for (int i = 0; i < 2; ++i) {
            const int idx = tid + i * 256;
            const int kr = idx >> 2, seg = idx & 3;
            const int p = (((kr >> 2) & 1) << 4) | (((kr >> 3) & 3) << 2) | (kr & 3);
            const int pos = (kr & ~31) | p;
            *(uint4*)&Ks[pos * 40 + seg * 8] = pk[i];
            const int dr = idx >> 4, vseg = idx & 15;
            *(uint4*)&Vs[dr * 168 + vseg * 8] = pv[i];
        }
        __syncthreads();
        if (kt < 3) {   // issue next tile's loads early; latency hides under compute
            #pragma unroll
            for (int i = 0; i < 2; ++i) {
                const int idx = tid + i * 256;
                pk[i] = *(const uint4*)(qk + ((size_t)b * 512 + (kt + 1) * 128 + (idx >> 2)) * 512
                                        + 256 + h * 32 + (idx & 3) * 8);
                pv[i] = *(const uint4*)(vt + (size_t)bh * 16384 + (idx >> 4) * 512
                                        + (kt + 1) * 128 + (idx & 15) * 8);
            }
        }

        // S^T frags: 8 x mfma(K, Q)
        f32x4_t s[8];
        __builtin_amdgcn_s_setprio(1);
        #pragma unroll
        for (int kf = 0; kf < 8; ++kf) {
            const bf16x8 kfrag = *(const bf16x8*)&Ks[(kf * 16 + c) * 40 + g * 8];
            s[kf] = __builtin_amdgcn_mfma_f32_16x16x32_bf16(kfrag, qf, zz, 0, 0, 0);
        }
        __builtin_amdgcn_s_setprio(0);

        // online softmax (each lane holds 32 keys of its q=c; reduce over g)
        float mt = s[0][0];
        #pragma unroll
        for (int kf = 0; kf < 8; ++kf)
            #pragma unroll
            for (int r = 0; r < 4; ++r) mt = fmaxf(mt, s[kf][r]);
        mt = fmaxf(mt, __shfl_xor(mt, 16));
        mt = fmaxf(mt, __shfl_xor(mt, 32));
        const float mn = fmaxf(m, mt);
        const float corr = __expf(m - mn);   // exp(-inf)=0 on first tile
        m = mn;
        float lt = 0.f;
        #pragma unroll
        for (int kf = 0; kf < 8; ++kf)
            #pragma unroll
            for (int r = 0; r < 4; ++r) {
                const float p = __expf(s[kf][r] - mn);
                s[kf][r] = p; lt += p;
            }
        lt += __shfl_xor(lt, 16);
        lt += __shfl_xor(lt, 32);
        l = l * corr + lt;
        #pragma unroll
        for (int r = 0; r < 4; ++r) { o0[r] *= corr; o1[r] *= corr; }

        // PV: P frags are lane-local (key permutation); O^T = V^T . P^T
        #pragma unroll
        for (int t = 0; t < 4; ++t) {
            union { uint u[4]; bf16x8 v; } pf;
            pf.u[0] = pack2(s[2*t][0],   s[2*t][1]);
            pf.u[1] = pack2(s[2*t][2],   s[2*t][3]);
            pf.u[2] = pack2(s[2*t+1][0], s[2*t+1][1]);
            pf.u[3] = pack2(s[2*t+1][2], s[2*t+1][3]);
            const bf16x8 va0 = *(const bf16x8*)&Vs[(0 * 16 + c) * 168 + t * 32 + g * 8];
            const bf16x8 va1 = *(const bf16x8*)&Vs[(1 * 16 + c) * 168 + t * 32 + g * 8];
            __builtin_amdgcn_s_setprio(1);
            o0 = __builtin_amdgcn_mfma_f32_16x16x32_bf16(va0, pf.v, o0, 0, 0, 0);
            o1 = __builtin_amdgcn_mfma_f32_16x16x32_bf16(va1, pf.v, o1, 0, 0, 0);
            __builtin_amdgcn_s_setprio(0);
        }
    }

    // epilogue: O^T[d][q]: lane holds q=c, d = df*16 + g*4 + r
    const float inv = 1.0f / l;
    const size_t obase = (qrow + c) * 256 + h * 32;
    #pragma unroll
    for (int r = 0; r < 4; ++r) {
        out[obase + g * 4 + r]      = f2bf(o0[r] * inv);
        out[obase + 16 + g * 4 + r] = f2bf(o1[r] * inv);
    }
}

// ---------------------------------------------------------------------------
// x = LN(x + resid) in fp32 (in-place on x) + bf16 copy to xb.
// ---------------------------------------------------------------------------
__global__ __launch_bounds__(256)
void add_ln2_kernel(float* __restrict__ x, const float* __restrict__ resid,
                    const float* __restrict__ w, const float* __restrict__ b,
                    ushort* __restrict__ xb)
{
    const int lane = threadIdx.x & 63;
    const int wv = threadIdx.x >> 6;
    const size_t row = (size_t)blockIdx.x * 4 + wv;
    float4 val = *(const float4*)(x + row * E_SZ + lane * 4);
    if (resid) {
        const float4 r = *(const float4*)(resid + row * E_SZ + lane * 4);
        val.x += r.x; val.y += r.y; val.z += r.z; val.w += r.w;
    }
    float s  = val.x + val.y + val.z + val.w;
    float ss = val.x * val.x + val.y * val.y + val.z * val.z + val.w * val.w;
    #pragma unroll
    for (int off = 1; off < 64; off <<= 1) {
        s  += __shfl_xor(s, off, 64);
        ss += __shfl_xor(ss, off, 64);
    }
    const float mu  = s * (1.0f / 256.0f);
    const float var = ss * (1.0f / 256.0f) - mu * mu;
    const float rs  = rsqrtf(var + 1e-5f);
    const float4 wv4 = *(const float4*)(w + lane * 4);
    const float4 bv4 = *(const float4*)(b + lane * 4);
    float4 o;
    o.x = (val.x - mu) * rs * wv4.x + bv4.x;
    o.y = (val.y - mu) * rs * wv4.y + bv4.y;
    o.z = (val.z - mu) * rs * wv4.z + bv4.z;
    o.w = (val.w - mu) * rs * wv4.w + bv4.w;
    *(float4*)(x + row * E_SZ + lane * 4) = o;
    ushort4 ob;
    ob.x = f2bf(o.x); ob.y = f2bf(o.y); ob.z = f2bf(o.z); ob.w = f2bf(o.w);
    *(ushort4*)(xb + row * E_SZ + lane * 4) = ob;
}

// ---------------------------------------------------------------------------
extern "C" void kernel_launch(void* const* d_in, const int* in_sizes, int n_in,
                              void* d_out, int out_size, void* d_ws, size_t ws_size,
                              hipStream_t stream)
{
    const float* cnn   = (const float*)d_in[0];
    const float* cnn_w = (const float*)d_in[1];
    const float* cnn_b = (const float*)d_in[2];
    const float* tok   = (const float*)d_in[3];
    const float* Wq    = (const float*)d_in[4];
    const float* bq    = (const float*)d_in[5];
    const float* Wk    = (const float*)d_in[6];
    const float* bk    = (const float*)d_in[7];
    const float* Wv    = (const float*)d_in[8];
    const float* bv    = (const float*)d_in[9];
    const float* Wo    = (const float*)d_in[10];
    const float* bo    = (const float*)d_in[11];
    const float* ln1w  = (const float*)d_in[12];
    const float* ln1b  = (const float*)d_in[13];
    const float* ln2w  = (const float*)d_in[14];
    const float* ln2b  = (const float*)d_in[15];
    const float* mw1   = (const float*)d_in[16];
    const float* mb1   = (const float*)d_in[17];
    const float* mw2   = (const float*)d_in[18];
    const float* mb2   = (const float*)d_in[19];
    const float* lnfw  = (const float*)d_in[20];
    const float* lnfb  = (const float*)d_in[21];
    const float* ow1   = (const float*)d_in[22];
    const float* ob1   = (const float*)d_in[23];
    const float* ow2   = (const float*)d_in[24];
    const float* ob2   = (const float*)d_in[25];

    const int M = N_TOK;
    char* ws = (char*)d_ws;

    // Workspace layout (byte offsets in MB):
    // [0,16)  x fp32          [16,24) xb bf16       [24,40) qkb / resid / cnnb
    // [40,48) vt bf16         [48,56) ab bf16       [40,64) hb bf16 (aliases vt+ab)
    // [64,~71) converted weights + bqkv
    float*  x     = (float*)(ws + 0);
    ushort* xb    = (ushort*)(ws + 16 * MB);
    ushort* qkb   = (ushort*)(ws + 24 * MB);
    float*  resid = (float*)(ws + 24 * MB);
    ushort* cnnb  = (ushort*)(ws + 24 * MB);
    ushort* vt    = (ushort*)(ws + 40 * MB);
    ushort* ab_   = (ushort*)(ws + 48 * MB);
    ushort* hb_   = (ushort*)(ws + 40 * MB);
    ushort* wb    = (ushort*)(ws + 64 * MB);

    ushort* cnn_wb = wb;                    // 131072
    ushort* Wob    = wb + 131072;           // 262144
    ushort* wqkv   = wb + 393216;           // 786432 = [L][768][256]
    ushort* mw1b   = wb + 1179648;          // 786432
    ushort* mw2b   = wb + 1966080;          // 786432
    ushort* ow1b   = wb + 2752512;          // 131072
    ushort* ow2b   = wb + 2883584;          // 262144
    float*  bqkv   = (float*)(ws + 64 * MB + 6291456);   // [L][768] fp32

    // conversions
    cvt_kernel<<<dim3(4096), dim3(256), 0, stream>>>(cnn, cnnb);
    cvt_kernel<<<dim3(64),  dim3(256), 0, stream>>>(cnn_w, cnn_wb);
    cvt_kernel<<<dim3(128), dim3(256), 0, stream>>>(Wo, Wob);
    cvt_kernel<<<dim3(384), dim3(256), 0, stream>>>(mw1, mw1b);
    cvt_kernel<<<dim3(384), dim3(256), 0, stream>>>(mw2, mw2b);
    cvt_kernel<<<dim3(64),  dim3(256), 0, stream>>>(ow1, ow1b);
    cvt_kernel<<<dim3(128), dim3(256), 0, stream>>>(ow2, ow2b);
    wqkv_cvt_kernel<<<dim3(384), dim3(256), 0, stream>>>(Wq, Wk, Wv, wqkv);
    bqkv_kernel<<<dim3(12), dim3(256), 0, stream>>>(bq, bk, bv, bqkv);

    // x = cnn @ cnn_w^T + cnn_b + tok[0]  -> x fp32 + xb bf16
    gemm_bf16_kernel<0, 0, true, true><<<dim3(M / 128, E_SZ / 64), dim3(256), 0, stream>>>(
        cnnb, cnn_wb, cnn_b, tok, x, xb, nullptr, M, C_SZ, E_SZ);

    for (int i = 0; i < L_SZ; ++i) {
        // fused QKV: q|k -> qkb [N][512], v -> vt transposed [b][h][32][512]
        gemm_bf16_kernel<0, 1, false, false><<<dim3(M / 128, HID / 64), dim3(256), 0, stream>>>(
            xb, wqkv + (size_t)i * 196608, bqkv + (size_t)i * 768, nullptr,
            nullptr, qkb, vt, M, E_SZ, HID);

        attn_v3<<<dim3(B_SZ * H_SZ, S_SZ / 64), dim3(256), 0, stream>>>(qkb, vt, ab_);

        // attn_out = ab @ Wo^T + bo -> resid fp32
        gemm_bf16_kernel<0, 0, true, false><<<dim3(M / 128, E_SZ / 64), dim3(256), 0, stream>>>(
            ab_, Wob + (size_t)i * 65536, bo + (size_t)i * E_SZ, nullptr,
            resid, nullptr, nullptr, M, E_SZ, E_SZ);
        add_ln2_kernel<<<dim3(M / 4), dim3(256), 0, stream>>>(
            x, resid, ln1w + (size_t)i * E_SZ, ln1b + (size_t)i * E_SZ, xb);

        gemm_bf16_kernel<1, 0, false, true><<<dim3(M / 128, HID / 64), dim3(256), 0, stream>>>(
            xb, mw1b + (size_t)i * HID * E_SZ, mb1 + (size_t)i * HID, nullptr,
            nullptr, hb_, nullptr, M, E_SZ, HID);
        gemm_bf16_kernel<0, 0, true, false><<<dim3(M / 128, E_SZ / 64), dim3(256), 0, stream>>>(
            hb_, mw2b + (size_t)i * E_SZ * HID, mb2 + (size_t)i * E_SZ, nullptr,
            resid, nullptr, nullptr, M, HID, E_SZ);
        add_ln2_kernel<<<dim3(M / 4), dim3(256), 0, stream>>>(
            x, resid, ln2w + (size_t)i * E_SZ, ln2b + (size_t)i * E_SZ, xb);
    }

    // final LN -> xb
    add_ln2_kernel<<<dim3(M / 4), dim3(256), 0, stream>>>(x, nullptr, lnfw, lnfb, xb);

    // h = gelu(xb @ ow1^T + ob1) -> hb_ [N,512]
    gemm_bf16_kernel<1, 0, false, true><<<dim3(M / 128, (2 * E_SZ) / 64), dim3(256), 0, stream>>>(
        xb, ow1b, ob1, nullptr, nullptr, hb_, nullptr, M, E_SZ, 2 * E_SZ);
    // out = relu(hb @ ow2^T + ob2) -> d_out fp32
    gemm_bf16_kernel<2, 0, true, false><<<dim3(M / 128, C_SZ / 64), dim3(256), 0, stream>>>(
        hb_, ow2b, ob2, nullptr, (float*)d_out, nullptr, nullptr, M, 2 * E_SZ, C_SZ);
}

// Round 6
// 578.789 us; speedup vs baseline: 1.1906x; 1.1906x over previous
//
#include <hip/hip_runtime.h>
#include <hip/hip_bf16.h>
#include <math.h>

// Problem dims
#define B_SZ 32
#define S_SZ 512
#define C_SZ 512
#define E_SZ 256
#define H_SZ 8
#define D_SZ 32
#define L_SZ 4
#define N_TOK (B_SZ * S_SZ)   // 16384
#define HID 768               // 3*E
#define MB (1048576)

typedef __attribute__((ext_vector_type(8))) short bf16x8;
typedef __attribute__((ext_vector_type(4))) float f32x4_t;

__device__ __forceinline__ float gelu_f(float x) {
    return 0.5f * x * (1.0f + erff(x * 0.70710678118654752f));
}

__device__ __forceinline__ ushort f2bf(float f) {
    uint u = __float_as_uint(f);
    return (ushort)((u + 0x7FFFu + ((u >> 16) & 1u)) >> 16);
}
// RTNE pair-convert; lowers to v_cvt_pk_bf16_f32 on gfx950
__device__ __forceinline__ uint pack2(float a, float b) {
    __hip_bfloat162 h = __float22bfloat162_rn(make_float2(a, b));
    union { __hip_bfloat162 h; uint u; } c; c.h = h;
    return c.u;
}
__device__ __forceinline__ void unpack8(uint4 u, float* f) {
    f[0] = __uint_as_float((u.x & 0xFFFFu) << 16); f[1] = __uint_as_float(u.x & 0xFFFF0000u);
    f[2] = __uint_as_float((u.y & 0xFFFFu) << 16); f[3] = __uint_as_float(u.y & 0xFFFF0000u);
    f[4] = __uint_as_float((u.z & 0xFFFFu) << 16); f[5] = __uint_as_float(u.z & 0xFFFF0000u);
    f[6] = __uint_as_float((u.w & 0xFFFFu) << 16); f[7] = __uint_as_float(u.w & 0xFFFF0000u);
}

// async global->LDS, 16B per lane; LDS dest = wave-uniform base + lane*16
__device__ __forceinline__ void gload16(const ushort* g, ushort* l) {
    __builtin_amdgcn_global_load_lds(
        (const __attribute__((address_space(1))) void*)g,
        (__attribute__((address_space(3))) void*)l, 16, 0, 0);
}

// ---------------------------------------------------------------------------
// fp32 -> bf16 conversion (n % 2048 == 0, grid = n/2048)
// ---------------------------------------------------------------------------
__global__ __launch_bounds__(256)
void cvt_kernel(const float* __restrict__ src, ushort* __restrict__ dst)
{
    const int i = (blockIdx.x * 256 + threadIdx.x) * 8;
    const float4 a = *(const float4*)(src + i);
    const float4 b = *(const float4*)(src + i + 4);
    uint4 o;
    o.x = pack2(a.x, a.y); o.y = pack2(a.z, a.w);
    o.z = pack2(b.x, b.y); o.w = pack2(b.z, b.w);
    *(uint4*)(dst + i) = o;
}

// merged Wq/Wk/Wv conversion -> wqkv[L][3][256][256]; grid 384 x 256
__global__ __launch_bounds__(256)
void wqkv_cvt_kernel(const float* __restrict__ Wq, const float* __restrict__ Wk,
                     const float* __restrict__ Wv, ushort* __restrict__ dst)
{
    const int i = (blockIdx.x * 256 + threadIdx.x) * 8;   // < 786432
    const int layer = i / 196608;
    const int rem = i - layer * 196608;
    const int sub = rem >> 16, off = rem & 65535;
    const float* src = (sub == 0 ? Wq : sub == 1 ? Wk : Wv) + layer * 65536 + off;
    const float4 a = *(const float4*)src;
    const float4 b = *(const float4*)(src + 4);
    uint4 o;
    o.x = pack2(a.x, a.y); o.y = pack2(a.z, a.w);
    o.z = pack2(b.x, b.y); o.w = pack2(b.z, b.w);
    *(uint4*)(dst + i) = o;
}

// concat per-layer q/k/v biases -> bqkv[L][768]; grid 12 x 256
__global__ __launch_bounds__(256)
void bqkv_kernel(const float* __restrict__ bq, const float* __restrict__ bk,
                 const float* __restrict__ bv, float* __restrict__ dst)
{
    const int idx = blockIdx.x * 256 + threadIdx.x;   // 0..3071
    const int layer = idx / 768, j = idx % 768;
    float v = (j < 256) ? bq[layer * 256 + j]
            : (j < 512) ? bk[layer * 256 + j - 256]
                        : bv[layer * 256 + j - 512];
    dst[layer * 768 + j] = v;
}

// ---------------------------------------------------------------------------
// bf16 MFMA GEMM: C[M,F] = A[M,K](bf16) @ W[F,K](bf16)^T + bias (+bias2), ACT
// Tile 128x64, BK=64, 4 waves (2x2). Staging via global_load_lds (16B/lane)
// into double-buffered linear LDS [rows][64]; k-seg XOR-swizzled on the
// global SOURCE (seg ^= row&7) and on the ds_read side -> uniform 8-slot
// access (optimal for b128). One barrier per K-step (16 MFMA/step).
// EPI=1: fused QKV split (q|k -> Cb [N][512], v -> Cb2 [b][h][32][512]).
// K % 64 == 0.
// ---------------------------------------------------------------------------
template<int ACT, int EPI, bool OF, bool OB>
__global__ __launch_bounds__(256)
void gemm_bf16_kernel(const ushort* __restrict__ A, const ushort* __restrict__ W,
                      const float* __restrict__ bias, const float* __restrict__ bias2,
                      float* __restrict__ Cf, ushort* __restrict__ Cb,
                      ushort* __restrict__ Cb2, int M, int K, int F)
{
    __shared__ __align__(16) ushort As[2][128 * 64];   // 16KB x2
    __shared__ __align__(16) ushort Bs[2][64 * 64];    // 8KB x2
    const int tid = threadIdx.x;
    const int bm = blockIdx.x * 128, bn = blockIdx.y * 64;
    const int lane = tid & 63, w = tid >> 6;
    const int lr8 = lane >> 3, lseg = lane & 7;
    const int lsx = lseg ^ lr8;                        // source-side swizzle
    const int wm = w >> 1, wn = w & 1;
    const int fr = lane & 15, fk = lane >> 4;
    const int fx = fr & 7;                             // read-side swizzle bits
    f32x4_t acc[4][2] = {};

    const ushort* Ag = A + (size_t)(bm + w * 32 + lr8) * K + lsx * 8;
    const ushort* Wg = W + (size_t)(bn + w * 16 + lr8) * K + lsx * 8;

    // prologue: stage tile 0 into buf 0
    #pragma unroll
    for (int q = 0; q < 4; ++q) gload16(Ag + (size_t)q * 8 * K, &As[0][(w * 32 + q * 8) * 64]);
    #pragma unroll
    for (int q = 0; q < 2; ++q) gload16(Wg + (size_t)q * 8 * K, &Bs[0][(w * 16 + q * 8) * 64]);
    __syncthreads();

    const int NT = K >> 6;
    int cur = 0;
    for (int t = 0; t < NT; ++t) {
        if (t + 1 < NT) {                              // stage next into cur^1
            const size_t k0 = (size_t)(t + 1) << 6;
            #pragma unroll
            for (int q = 0; q < 4; ++q)
                gload16(Ag + (size_t)q * 8 * K + k0, &As[cur ^ 1][(w * 32 + q * 8) * 64]);
            #pragma unroll
            for (int q = 0; q < 2; ++q)
                gload16(Wg + (size_t)q * 8 * K + k0, &Bs[cur ^ 1][(w * 16 + q * 8) * 64]);
        }
        bf16x8 af[2][4], bw[2][2];
        #pragma unroll
        for (int kk = 0; kk < 2; ++kk) {
            const int rs = ((kk * 4 + fk) ^ fx) * 8;
            #pragma unroll
            for (int i = 0; i < 4; ++i)
                af[kk][i] = *(const bf16x8*)&As[cur][(wm * 64 + i * 16 + fr) * 64 + rs];
            #pragma unroll
            for (int j = 0; j < 2; ++j)
                bw[kk][j] = *(const bf16x8*)&Bs[cur][(wn * 32 + j * 16 + fr) * 64 + rs];
        }
        #pragma unroll
        for (int kk = 0; kk < 2; ++kk)
            #pragma unroll
            for (int i = 0; i < 4; ++i)
                #pragma unroll
                for (int j = 0; j < 2; ++j)
                    acc[i][j] = __builtin_amdgcn_mfma_f32_16x16x32_bf16(af[kk][i], bw[kk][j], acc[i][j], 0, 0, 0);
        __syncthreads();                               // drains this iter's DMA
        cur ^= 1;
    }

    // C/D layout: col = lane&15, row = (lane>>4)*4 + reg.
    #pragma unroll
    for (int j = 0; j < 2; ++j) {
        const int col = bn + wn * 32 + j * 16 + fr;
        float bb = bias[col];
        if (bias2) bb += bias2[col];
        #pragma unroll
        for (int i = 0; i < 4; ++i) {
            #pragma unroll
            for (int r = 0; r < 4; ++r) {
                const int row = bm + wm * 64 + i * 16 + fk * 4 + r;
                float t = acc[i][j][r] + bb;
                if (ACT == 1) t = gelu_f(t);
                if (ACT == 2) t = fmaxf(t, 0.0f);
                if (EPI == 1) {
                    const int b2 = row >> 9, s2 = row & 511;
                    if (col < 512) {
                        Cb[(size_t)row * 512 + col] = f2bf(t);
                    } else {
                        const int cc = col - 512;
                        Cb2[(size_t)(((b2 << 3) + (cc >> 5)) << 14) + ((cc & 31) << 9) + s2] = f2bf(t);
                    }
                } else {
                    if (OF) Cf[(size_t)row * F + col] = t;
                    if (OB) Cb[(size_t)row * F + col] = f2bf(t);
                }
            }
        }
    }
}

// ---------------------------------------------------------------------------
// MFMA flash attention v4. Grid (B*H); block 512 = 8 waves, 1 block/CU.
// All of K (permuted, [512][40] ushort) and V^T ([32][520]) staged to LDS
// ONCE; one barrier; then pure LDS-resident compute. Each wave processes 4
// q-groups of 16 rows (8 waves x 4 x 16 = 512 q rows). Swapped QK^T +
// permuted K rows -> P frags land in PV B-operand layout with zero shuffles.
// qk: [N][512] bf16 (q cols 0..255, k cols 256..511, head h at h*32).
// vt: [b][h][32][512] bf16. out: [N][256] bf16.
// ---------------------------------------------------------------------------
__global__ __launch_bounds__(512)
void attn_v4(const ushort* __restrict__ qk, const ushort* __restrict__ vt,
             ushort* __restrict__ out)
{
    __shared__ __align__(16) ushort Ks[512 * 40];   // 40 KB
    __shared__ __align__(16) ushort Vs[32 * 520];   // 33.3 KB
    const int bh = blockIdx.x;
    const int b = bh >> 3, h = bh & 7;
    const int tid = threadIdx.x;                    // 0..511
    const int w = tid >> 6, lane = tid & 63;
    const int g = lane >> 4, c = lane & 15;

    // stage all K (permuted within each 32-key block) and all V^T
    #pragma unroll
    for (int i = 0; i < 4; ++i) {
        const int idx = tid + i * 512;              // 0..2047
        const int kr = idx >> 2, seg = idx & 3;
        const uint4 kv = *(const uint4*)(qk + ((size_t)b * 512 + kr) * 512
                                         + 256 + h * 32 + seg * 8);
        const int p = (((kr >> 2) & 1) << 4) | (((kr >> 3) & 3) << 2) | (kr & 3);
        const int pos = (kr & ~31) | p;
        *(uint4*)&Ks[pos * 40 + seg * 8] = kv;
        const int dr = idx >> 6, vseg = idx & 63;
        const uint4 vv = *(const uint4*)(vt + (size_t)bh * 16384 + dr * 512 + vseg * 8);
        *(uint4*)&Vs[dr * 520 + vseg * 8] = vv;
    }

    // load + pre-scale this wave's 4 Q fragments (qg j -> q rows (j*8+w)*16..+15)
    bf16x8 qf[4];
    #pragma unroll
    for (int j = 0; j < 4; ++j) {
        const size_t qrow = (size_t)b * 512 + (j * 8 + w) * 16 + c;
        const uint4 qv = *(const uint4*)(qk + qrow * 512 + h * 32 + g * 8);
        float f[8]; unpack8(qv, f);
        const float scale = 0.17677669529663689f;
        union { uint u[4]; bf16x8 v; } qq;
        #pragma unroll
        for (int t = 0; t < 4; ++t) qq.u[t] = pack2(f[2*t] * scale, f[2*t+1] * scale);
        qf[j] = qq.v;
    }
    __syncthreads();

    const f32x4_t zz = {0.f, 0.f, 0.f, 0.f};
    #pragma unroll
    for (int j = 0; j < 4; ++j) {
        float m = -INFINITY, l = 0.f;
        f32x4_t o0 = zz, o1 = zz;
        for (int kt = 0; kt < 4; ++kt) {
            const int kbase = kt * 128;
            // S^T frags: 8 x mfma(K, Q)
            f32x4_t s[8];
            __builtin_amdgcn_s_setprio(1);
            #pragma unroll
            for (int kf = 0; kf < 8; ++kf) {
                const bf16x8 kfrag = *(const bf16x8*)&Ks[(kbase + kf * 16 + c) * 40 + g * 8];
                s[kf] = __builtin_amdgcn_mfma_f32_16x16x32_bf16(kfrag, qf[j], zz, 0, 0, 0);
            }
            __builtin_amdgcn_s_setprio(0);

            // online softmax (lane holds 32 keys of its q=c; reduce over g)
            float mt = s[0][0];
            #pragma unroll
            for (int kf = 0; kf < 8; ++kf)
                #pragma unroll
                for (int r = 0; r < 4; ++r) mt = fmaxf(mt, s[kf][r]);
            mt = fmaxf(mt, __shfl_xor(mt, 16));
            mt = fmaxf(mt, __shfl_xor(mt, 32));
            const float mn = fmaxf(m, mt);
            const float corr = __expf(m - mn);   // exp(-inf)=0 on first tile
            m = mn;
            float lt = 0.f;
            #pragma unroll
            for (int kf = 0; kf < 8; ++kf)
                #pragma unroll
                for (int r = 0; r < 4; ++r) {
                    const float p = __expf(s[kf][r] - mn);
                    s[kf][r] = p; lt += p;
                }
            lt += __shfl_xor(lt, 16);
            lt += __shfl_xor(lt, 32);
            l = l * corr + lt;
            #pragma unroll
            for (int r = 0; r < 4; ++r) { o0[r] *= corr; o1[r] *= corr; }

            // PV: P frags are lane-local (key permutation); O^T = V^T . P^T
            #pragma unroll
            for (int t = 0; t < 4; ++t) {
                union { uint u[4]; bf16x8 v; } pf;
                pf.u[0] = pack2(s[2*t][0],   s[2*t][1]);
                pf.u[1] = pack2(s[2*t][2],   s[2*t][3]);
                pf.u[2] = pack2(s[2*t+1][0], s[2*t+1][1]);
                pf.u[3] = pack2(s[2*t+1][2], s[2*t+1][3]);
                const bf16x8 va0 = *(const bf16x8*)&Vs[c * 520 + kbase + t * 32 + g * 8];
                const bf16x8 va1 = *(const bf16x8*)&Vs[(16 + c) * 520 + kbase + t * 32 + g * 8];
                __builtin_amdgcn_s_setprio(1);
                o0 = __builtin_amdgcn_mfma_f32_16x16x32_bf16(va0, pf.v, o0, 0, 0, 0);
                o1 = __builtin_amdgcn_mfma_f32_16x16x32_bf16(va1, pf.v, o1, 0, 0, 0);
                __builtin_amdgcn_s_setprio(0);
            }
        }

        // epilogue: O^T[d][q]: lane holds q=c, d = df*16 + g*4 + r
        const float inv = 1.0f / l;
        const size_t obase = ((size_t)b * 512 + (j * 8 + w) * 16 + c) * 256 + h * 32;
        ushort4 w0, w1;
        w0.x = f2bf(o0[0] * inv); w0.y = f2bf(o0[1] * inv);
        w0.z = f2bf(o0[2] * inv); w0.w = f2bf(o0[3] * inv);
        w1.x = f2bf(o1[0] * inv); w1.y = f2bf(o1[1] * inv);
        w1.z = f2bf(o1[2] * inv); w1.w = f2bf(o1[3] * inv);
        *(ushort4*)(out + obase + g * 4)      = w0;
        *(ushort4*)(out + obase + 16 + g * 4) = w1;
    }
}

// ---------------------------------------------------------------------------
// x = LN(x + resid) in fp32 (in-place on x) + bf16 copy to xb.
// ---------------------------------------------------------------------------
__global__ __launch_bounds__(256)
void add_ln2_kernel(float* __restrict__ x, const float* __restrict__ resid,
                    const float* __restrict__ w, const float* __restrict__ b,
                    ushort* __restrict__ xb)
{
    const int lane = threadIdx.x & 63;
    const int wv = threadIdx.x >> 6;
    const size_t row = (size_t)blockIdx.x * 4 + wv;
    float4 val = *(const float4*)(x + row * E_SZ + lane * 4);
    if (resid) {
        const float4 r = *(const float4*)(resid + row * E_SZ + lane * 4);
        val.x += r.x; val.y += r.y; val.z += r.z; val.w += r.w;
    }
    float s  = val.x + val.y + val.z + val.w;
    float ss = val.x * val.x + val.y * val.y + val.z * val.z + val.w * val.w;
    #pragma unroll
    for (int off = 1; off < 64; off <<= 1) {
        s  += __shfl_xor(s, off, 64);
        ss += __shfl_xor(ss, off, 64);
    }
    const float mu  = s * (1.0f / 256.0f);
    const float var = ss * (1.0f / 256.0f) - mu * mu;
    const float rs  = rsqrtf(var + 1e-5f);
    const float4 wv4 = *(const float4*)(w + lane * 4);
    const float4 bv4 = *(const float4*)(b + lane * 4);
    float4 o;
    o.x = (val.x - mu) * rs * wv4.x + bv4.x;
    o.y = (val.y - mu) * rs * wv4.y + bv4.y;
    o.z = (val.z - mu) * rs * wv4.z + bv4.z;
    o.w = (val.w - mu) * rs * wv4.w + bv4.w;
    *(float4*)(x + row * E_SZ + lane * 4) = o;
    ushort4 ob;
    ob.x = f2bf(o.x); ob.y = f2bf(o.y); ob.z = f2bf(o.z); ob.w = f2bf(o.w);
    *(ushort4*)(xb + row * E_SZ + lane * 4) = ob;
}

// ---------------------------------------------------------------------------
extern "C" void kernel_launch(void* const* d_in, const int* in_sizes, int n_in,
                              void* d_out, int out_size, void* d_ws, size_t ws_size,
                              hipStream_t stream)
{
    const float* cnn   = (const float*)d_in[0];
    const float* cnn_w = (const float*)d_in[1];
    const float* cnn_b = (const float*)d_in[2];
    const float* tok   = (const float*)d_in[3];
    const float* Wq    = (const float*)d_in[4];
    const float* bq    = (const float*)d_in[5];
    const float* Wk    = (const float*)d_in[6];
    const float* bk    = (const float*)d_in[7];
    const float* Wv    = (const float*)d_in[8];
    const float* bv    = (const float*)d_in[9];
    const float* Wo    = (const float*)d_in[10];
    const float* bo    = (const float*)d_in[11];
    const float* ln1w  = (const float*)d_in[12];
    const float* ln1b  = (const float*)d_in[13];
    const float* ln2w  = (const float*)d_in[14];
    const float* ln2b  = (const float*)d_in[15];
    const float* mw1   = (const float*)d_in[16];
    const float* mb1   = (const float*)d_in[17];
    const float* mw2   = (const float*)d_in[18];
    const float* mb2   = (const float*)d_in[19];
    const float* lnfw  = (const float*)d_in[20];
    const float* lnfb  = (const float*)d_in[21];
    const float* ow1   = (const float*)d_in[22];
    const float* ob1   = (const float*)d_in[23];
    const float* ow2   = (const float*)d_in[24];
    const float* ob2   = (const float*)d_in[25];

    const int M = N_TOK;
    char* ws = (char*)d_ws;

    // Workspace layout (byte offsets in MB):
    // [0,16)  x fp32          [16,24) xb bf16       [24,40) qkb / resid / cnnb
    // [40,48) vt bf16         [48,56) ab bf16       [40,64) hb bf16 (aliases vt+ab)
    // [64,~71) converted weights + bqkv
    float*  x     = (float*)(ws + 0);
    ushort* xb    = (ushort*)(ws + 16 * MB);
    ushort* qkb   = (ushort*)(ws + 24 * MB);
    float*  resid = (float*)(ws + 24 * MB);
    ushort* cnnb  = (ushort*)(ws + 24 * MB);
    ushort* vt    = (ushort*)(ws + 40 * MB);
    ushort* ab_   = (ushort*)(ws + 48 * MB);
    ushort* hb_   = (ushort*)(ws + 40 * MB);
    ushort* wb    = (ushort*)(ws + 64 * MB);

    ushort* cnn_wb = wb;                    // 131072
    ushort* Wob    = wb + 131072;           // 262144
    ushort* wqkv   = wb + 393216;           // 786432 = [L][768][256]
    ushort* mw1b   = wb + 1179648;          // 786432
    ushort* mw2b   = wb + 1966080;          // 786432
    ushort* ow1b   = wb + 2752512;          // 131072
    ushort* ow2b   = wb + 2883584;          // 262144
    float*  bqkv   = (float*)(ws + 64 * MB + 6291456);   // [L][768] fp32

    // conversions
    cvt_kernel<<<dim3(4096), dim3(256), 0, stream>>>(cnn, cnnb);
    cvt_kernel<<<dim3(64),  dim3(256), 0, stream>>>(cnn_w, cnn_wb);
    cvt_kernel<<<dim3(128), dim3(256), 0, stream>>>(Wo, Wob);
    cvt_kernel<<<dim3(384), dim3(256), 0, stream>>>(mw1, mw1b);
    cvt_kernel<<<dim3(384), dim3(256), 0, stream>>>(mw2, mw2b);
    cvt_kernel<<<dim3(64),  dim3(256), 0, stream>>>(ow1, ow1b);
    cvt_kernel<<<dim3(128), dim3(256), 0, stream>>>(ow2, ow2b);
    wqkv_cvt_kernel<<<dim3(384), dim3(256), 0, stream>>>(Wq, Wk, Wv, wqkv);
    bqkv_kernel<<<dim3(12), dim3(256), 0, stream>>>(bq, bk, bv, bqkv);

    // x = cnn @ cnn_w^T + cnn_b + tok[0]  -> x fp32 + xb bf16
    gemm_bf16_kernel<0, 0, true, true><<<dim3(M / 128, E_SZ / 64), dim3(256), 0, stream>>>(
        cnnb, cnn_wb, cnn_b, tok, x, xb, nullptr, M, C_SZ, E_SZ);

    for (int i = 0; i < L_SZ; ++i) {
        // fused QKV: q|k -> qkb [N][512], v -> vt transposed [b][h][32][512]
        gemm_bf16_kernel<0, 1, false, false><<<dim3(M / 128, HID / 64), dim3(256), 0, stream>>>(
            xb, wqkv + (size_t)i * 196608, bqkv + (size_t)i * 768, nullptr,
            nullptr, qkb, vt, M, E_SZ, HID);

        attn_v4<<<dim3(B_SZ * H_SZ), dim3(512), 0, stream>>>(qkb, vt, ab_);

        // attn_out = ab @ Wo^T + bo -> resid fp32
        gemm_bf16_kernel<0, 0, true, false><<<dim3(M / 128, E_SZ / 64), dim3(256), 0, stream>>>(
            ab_, Wob + (size_t)i * 65536, bo + (size_t)i * E_SZ, nullptr,
            resid, nullptr, nullptr, M, E_SZ, E_SZ);
        add_ln2_kernel<<<dim3(M / 4), dim3(256), 0, stream>>>(
            x, resid, ln1w + (size_t)i * E_SZ, ln1b + (size_t)i * E_SZ, xb);

        gemm_bf16_kernel<1, 0, false, true><<<dim3(M / 128, HID / 64), dim3(256), 0, stream>>>(
            xb, mw1b + (size_t)i * HID * E_SZ, mb1 + (size_t)i * HID, nullptr,
            nullptr, hb_, nullptr, M, E_SZ, HID);
        gemm_bf16_kernel<0, 0, true, false><<<dim3(M / 128, E_SZ / 64), dim3(256), 0, stream>>>(
            hb_, mw2b + (size_t)i * E_SZ * HID, mb2 + (size_t)i * E_SZ, nullptr,
            resid, nullptr, nullptr, M, HID, E_SZ);
        add_ln2_kernel<<<dim3(M / 4), dim3(256), 0, stream>>>(
            x, resid, ln2w + (size_t)i * E_SZ, ln2b + (size_t)i * E_SZ, xb);
    }

    // final LN -> xb
    add_ln2_kernel<<<dim3(M / 4), dim3(256), 0, stream>>>(x, nullptr, lnfw, lnfb, xb);

    // h = gelu(xb @ ow1^T + ob1) -> hb_ [N,512]
    gemm_bf16_kernel<1, 0, false, true><<<dim3(M / 128, (2 * E_SZ) / 64), dim3(256), 0, stream>>>(
        xb, ow1b, ob1, nullptr, nullptr, hb_, nullptr, M, E_SZ, 2 * E_SZ);
    // out = relu(hb @ ow2^T + ob2) -> d_out fp32
    gemm_bf16_kernel<2, 0, true, false><<<dim3(M / 128, C_SZ / 64), dim3(256), 0, stream>>>(
        hb_, ow2b, ob2, nullptr, (float*)d_out, nullptr, nullptr, M, 2 * E_SZ, C_SZ);
}

// Round 7
// 522.691 us; speedup vs baseline: 1.3184x; 1.1073x over previous
//
#include <hip/hip_runtime.h>
#include <hip/hip_bf16.h>
#include <math.h>

// Problem dims
#define B_SZ 32
#define S_SZ 512
#define C_SZ 512
#define E_SZ 256
#define H_SZ 8
#define D_SZ 32
#define L_SZ 4
#define N_TOK (B_SZ * S_SZ)   // 16384
#define HID 768               // 3*E
#define MB (1048576)

typedef __attribute__((ext_vector_type(8))) short bf16x8;
typedef __attribute__((ext_vector_type(4))) float f32x4_t;

__device__ __forceinline__ float gelu_f(float x) {
    return 0.5f * x * (1.0f + erff(x * 0.70710678118654752f));
}

__device__ __forceinline__ ushort f2bf(float f) {
    uint u = __float_as_uint(f);
    return (ushort)((u + 0x7FFFu + ((u >> 16) & 1u)) >> 16);
}
// RTNE pair-convert; lowers to v_cvt_pk_bf16_f32 on gfx950
__device__ __forceinline__ uint pack2(float a, float b) {
    __hip_bfloat162 h = __float22bfloat162_rn(make_float2(a, b));
    union { __hip_bfloat162 h; uint u; } c; c.h = h;
    return c.u;
}
__device__ __forceinline__ void unpack8(uint4 u, float* f) {
    f[0] = __uint_as_float((u.x & 0xFFFFu) << 16); f[1] = __uint_as_float(u.x & 0xFFFF0000u);
    f[2] = __uint_as_float((u.y & 0xFFFFu) << 16); f[3] = __uint_as_float(u.y & 0xFFFF0000u);
    f[4] = __uint_as_float((u.z & 0xFFFFu) << 16); f[5] = __uint_as_float(u.z & 0xFFFF0000u);
    f[6] = __uint_as_float((u.w & 0xFFFFu) << 16); f[7] = __uint_as_float(u.w & 0xFFFF0000u);
}

// async global->LDS, 16B per lane; LDS dest = wave-uniform base + lane*16
__device__ __forceinline__ void gload16(const ushort* g, ushort* l) {
    __builtin_amdgcn_global_load_lds(
        (const __attribute__((address_space(1))) void*)g,
        (__attribute__((address_space(3))) void*)l, 16, 0, 0);
}

// ---------------------------------------------------------------------------
// fp32 -> bf16 conversion (n % 2048 == 0, grid = n/2048)
// ---------------------------------------------------------------------------
__global__ __launch_bounds__(256)
void cvt_kernel(const float* __restrict__ src, ushort* __restrict__ dst)
{
    const int i = (blockIdx.x * 256 + threadIdx.x) * 8;
    const float4 a = *(const float4*)(src + i);
    const float4 b = *(const float4*)(src + i + 4);
    uint4 o;
    o.x = pack2(a.x, a.y); o.y = pack2(a.z, a.w);
    o.z = pack2(b.x, b.y); o.w = pack2(b.z, b.w);
    *(uint4*)(dst + i) = o;
}

// ---------------------------------------------------------------------------
// ALL weight conversions in one kernel -> contiguous wb region.
// Layout (ushort offsets): cnn_w @0, Wo @131072, wqkv(interleaved) @393216,
// mw1 @1179648, mw2 @1966080, ow1 @2752512, ow2 @2883584, end 3145728.
// grid 1536 x 256 (3145728 / 2048).
// ---------------------------------------------------------------------------
__global__ __launch_bounds__(256)
void wcvt_kernel(const float* __restrict__ cnn_w, const float* __restrict__ Wo,
                 const float* __restrict__ Wq, const float* __restrict__ Wk,
                 const float* __restrict__ Wv, const float* __restrict__ mw1,
                 const float* __restrict__ mw2, const float* __restrict__ ow1,
                 const float* __restrict__ ow2, ushort* __restrict__ wb)
{
    const int i = (blockIdx.x * 256 + threadIdx.x) * 8;
    const float* src;
    if (i < 131072)       src = cnn_w + i;
    else if (i < 393216)  src = Wo + (i - 131072);
    else if (i < 1179648) {
        const int r = i - 393216;
        const int layer = r / 196608, rem = r % 196608;
        const int sub = rem >> 16, off = rem & 65535;
        src = (sub == 0 ? Wq : sub == 1 ? Wk : Wv) + layer * 65536 + off;
    }
    else if (i < 1966080) src = mw1 + (i - 1179648);
    else if (i < 2752512) src = mw2 + (i - 1966080);
    else if (i < 2883584) src = ow1 + (i - 2752512);
    else                  src = ow2 + (i - 2883584);
    const float4 a = *(const float4*)src;
    const float4 b = *(const float4*)(src + 4);
    uint4 o;
    o.x = pack2(a.x, a.y); o.y = pack2(a.z, a.w);
    o.z = pack2(b.x, b.y); o.w = pack2(b.z, b.w);
    *(uint4*)(wb + i) = o;
}

// concat per-layer q/k/v biases -> bqkv[L][768]; grid 12 x 256
__global__ __launch_bounds__(256)
void bqkv_kernel(const float* __restrict__ bq, const float* __restrict__ bk,
                 const float* __restrict__ bv, float* __restrict__ dst)
{
    const int idx = blockIdx.x * 256 + threadIdx.x;   // 0..3071
    const int layer = idx / 768, j = idx % 768;
    float v = (j < 256) ? bq[layer * 256 + j]
            : (j < 512) ? bk[layer * 256 + j - 256]
                        : bv[layer * 256 + j - 512];
    dst[layer * 768 + j] = v;
}

// ---------------------------------------------------------------------------
// bf16 MFMA GEMM: C[M,F] = A[M,K](bf16) @ W[F,K](bf16)^T + bias (+bias2), ACT
// Tile 128x64, BK=64, 4 waves (2x2). global_load_lds staging, dbuf,
// source/read XOR swizzle (seg ^= row&7). K % 64 == 0.
// EPI=1: fused QKV split (q|k -> Cb [N][512], v -> Cb2 [b][h][32][512]).
// ---------------------------------------------------------------------------
template<int ACT, int EPI, bool OF, bool OB>
__global__ __launch_bounds__(256)
void gemm_bf16_kernel(const ushort* __restrict__ A, const ushort* __restrict__ W,
                      const float* __restrict__ bias, const float* __restrict__ bias2,
                      float* __restrict__ Cf, ushort* __restrict__ Cb,
                      ushort* __restrict__ Cb2, int M, int K, int F)
{
    __shared__ __align__(16) ushort As[2][128 * 64];   // 16KB x2
    __shared__ __align__(16) ushort Bs[2][64 * 64];    // 8KB x2
    const int tid = threadIdx.x;
    const int bm = blockIdx.x * 128, bn = blockIdx.y * 64;
    const int lane = tid & 63, w = tid >> 6;
    const int lr8 = lane >> 3, lseg = lane & 7;
    const int lsx = lseg ^ lr8;                        // source-side swizzle
    const int wm = w >> 1, wn = w & 1;
    const int fr = lane & 15, fk = lane >> 4;
    const int fx = fr & 7;                             // read-side swizzle bits
    f32x4_t acc[4][2] = {};

    const ushort* Ag = A + (size_t)(bm + w * 32 + lr8) * K + lsx * 8;
    const ushort* Wg = W + (size_t)(bn + w * 16 + lr8) * K + lsx * 8;

    // prologue: stage tile 0 into buf 0
    #pragma unroll
    for (int q = 0; q < 4; ++q) gload16(Ag + (size_t)q * 8 * K, &As[0][(w * 32 + q * 8) * 64]);
    #pragma unroll
    for (int q = 0; q < 2; ++q) gload16(Wg + (size_t)q * 8 * K, &Bs[0][(w * 16 + q * 8) * 64]);
    __syncthreads();

    const int NT = K >> 6;
    int cur = 0;
    for (int t = 0; t < NT; ++t) {
        if (t + 1 < NT) {                              // stage next into cur^1
            const size_t k0 = (size_t)(t + 1) << 6;
            #pragma unroll
            for (int q = 0; q < 4; ++q)
                gload16(Ag + (size_t)q * 8 * K + k0, &As[cur ^ 1][(w * 32 + q * 8) * 64]);
            #pragma unroll
            for (int q = 0; q < 2; ++q)
                gload16(Wg + (size_t)q * 8 * K + k0, &Bs[cur ^ 1][(w * 16 + q * 8) * 64]);
        }
        bf16x8 af[2][4], bw[2][2];
        #pragma unroll
        for (int kk = 0; kk < 2; ++kk) {
            const int rs = ((kk * 4 + fk) ^ fx) * 8;
            #pragma unroll
            for (int i = 0; i < 4; ++i)
                af[kk][i] = *(const bf16x8*)&As[cur][(wm * 64 + i * 16 + fr) * 64 + rs];
            #pragma unroll
            for (int j = 0; j < 2; ++j)
                bw[kk][j] = *(const bf16x8*)&Bs[cur][(wn * 32 + j * 16 + fr) * 64 + rs];
        }
        #pragma unroll
        for (int kk = 0; kk < 2; ++kk)
            #pragma unroll
            for (int i = 0; i < 4; ++i)
                #pragma unroll
                for (int j = 0; j < 2; ++j)
                    acc[i][j] = __builtin_amdgcn_mfma_f32_16x16x32_bf16(af[kk][i], bw[kk][j], acc[i][j], 0, 0, 0);
        __syncthreads();                               // drains this iter's DMA
        cur ^= 1;
    }

    // C/D layout: col = lane&15, row = (lane>>4)*4 + reg.
    #pragma unroll
    for (int j = 0; j < 2; ++j) {
        const int col = bn + wn * 32 + j * 16 + fr;
        float bb = bias[col];
        if (bias2) bb += bias2[col];
        #pragma unroll
        for (int i = 0; i < 4; ++i) {
            #pragma unroll
            for (int r = 0; r < 4; ++r) {
                const int row = bm + wm * 64 + i * 16 + fk * 4 + r;
                float t = acc[i][j][r] + bb;
                if (ACT == 1) t = gelu_f(t);
                if (ACT == 2) t = fmaxf(t, 0.0f);
                if (EPI == 1) {
                    const int b2 = row >> 9, s2 = row & 511;
                    if (col < 512) {
                        Cb[(size_t)row * 512 + col] = f2bf(t);
                    } else {
                        const int cc = col - 512;
                        Cb2[(size_t)(((b2 << 3) + (cc >> 5)) << 14) + ((cc & 31) << 9) + s2] = f2bf(t);
                    }
                } else {
                    if (OF) Cf[(size_t)row * F + col] = t;
                    if (OB) Cb[(size_t)row * F + col] = f2bf(t);
                }
            }
        }
    }
}

// ---------------------------------------------------------------------------
// Fused GEMM + residual-add + LayerNorm (F = 256 only).
// x_new = LN(x + A@W^T + bias); writes x (fp32) and xb (bf16) in place.
// Tile BM=64 x BN=256: one block owns FULL rows -> LN per-row stats in-block.
// 512 threads = 8 waves; wave w owns cols w*32..w*32+31, all 64 rows.
// Same gload_lds + XOR-swizzle + dbuf K-loop as gemm_bf16_kernel. K%64==0.
// grid = M/64.
// ---------------------------------------------------------------------------
__global__ __launch_bounds__(512)
void gemm_ln_kernel(const ushort* __restrict__ A, const ushort* __restrict__ W,
                    const float* __restrict__ bias, float* __restrict__ x,
                    ushort* __restrict__ xb, const float* __restrict__ lnw,
                    const float* __restrict__ lnb, int K)
{
    __shared__ __align__(16) ushort As[2][64 * 64];    // 8KB x2
    __shared__ __align__(16) ushort Bs[2][256 * 64];   // 32KB x2
    __shared__ float psum[64][8], psq[64][8], murs[64][2];
    const int tid = threadIdx.x;
    const int bm = blockIdx.x * 64;
    const int lane = tid & 63, w = tid >> 6;
    const int lr8 = lane >> 3, lseg = lane & 7;
    const int lsx = lseg ^ lr8;
    const int fr = lane & 15, fk = lane >> 4;
    const int fx = fr & 7;
    f32x4_t acc[4][2] = {};

    const ushort* Ag = A + (size_t)(bm + w * 8 + lr8) * K + lsx * 8;
    const ushort* Wg = W + (size_t)(w * 32 + lr8) * K + lsx * 8;

    // prologue: stage tile 0 into buf 0 (A: 1 call/wave, B: 4 calls/wave)
    gload16(Ag, &As[0][(w * 8) * 64]);
    #pragma unroll
    for (int q = 0; q < 4; ++q) gload16(Wg + (size_t)q * 8 * K, &Bs[0][(w * 32 + q * 8) * 64]);
    __syncthreads();

    const int NT = K >> 6;
    int cur = 0;
    for (int t = 0; t < NT; ++t) {
        if (t + 1 < NT) {
            const size_t k0 = (size_t)(t + 1) << 6;
            gload16(Ag + k0, &As[cur ^ 1][(w * 8) * 64]);
            #pragma unroll
            for (int q = 0; q < 4; ++q)
                gload16(Wg + (size_t)q * 8 * K + k0, &Bs[cur ^ 1][(w * 32 + q * 8) * 64]);
        }
        bf16x8 af[2][4], bw[2][2];
        #pragma unroll
        for (int kk = 0; kk < 2; ++kk) {
            const int rs = ((kk * 4 + fk) ^ fx) * 8;
            #pragma unroll
            for (int i = 0; i < 4; ++i)
                af[kk][i] = *(const bf16x8*)&As[cur][(i * 16 + fr) * 64 + rs];
            #pragma unroll
            for (int j = 0; j < 2; ++j)
                bw[kk][j] = *(const bf16x8*)&Bs[cur][(w * 32 + j * 16 + fr) * 64 + rs];
        }
        #pragma unroll
        for (int kk = 0; kk < 2; ++kk)
            #pragma unroll
            for (int i = 0; i < 4; ++i)
                #pragma unroll
                for (int j = 0; j < 2; ++j)
                    acc[i][j] = __builtin_amdgcn_mfma_f32_16x16x32_bf16(af[kk][i], bw[kk][j], acc[i][j], 0, 0, 0);
        __syncthreads();
        cur ^= 1;
    }

    // ---- epilogue: y = acc + bias + x(resid), then per-row LN -------------
    float y[4][2][4];
    #pragma unroll
    for (int j = 0; j < 2; ++j) {
        const int col = w * 32 + j * 16 + fr;
        const float bb = bias[col];
        #pragma unroll
        for (int i = 0; i < 4; ++i)
            #pragma unroll
            for (int r = 0; r < 4; ++r) {
                const int row = i * 16 + fk * 4 + r;
                y[i][j][r] = acc[i][j][r] + bb + x[(size_t)(bm + row) * 256 + col];
            }
    }
    // per-lane partials over its 2 cols; reduce across the 16 fr lanes
    #pragma unroll
    for (int i = 0; i < 4; ++i)
        #pragma unroll
        for (int r = 0; r < 4; ++r) {
            float s = y[i][0][r] + y[i][1][r];
            float q = y[i][0][r] * y[i][0][r] + y[i][1][r] * y[i][1][r];
            #pragma unroll
            for (int off = 1; off < 16; off <<= 1) {
                s += __shfl_xor(s, off);
                q += __shfl_xor(q, off);
            }
            if (fr == 0) {
                psum[i * 16 + fk * 4 + r][w] = s;
                psq [i * 16 + fk * 4 + r][w] = q;
            }
        }
    __syncthreads();
    if (tid < 64) {
        float ms = 0.f, mq = 0.f;
        #pragma unroll
        for (int ww = 0; ww < 8; ++ww) { ms += psum[tid][ww]; mq += psq[tid][ww]; }
        const float mu = ms * (1.0f / 256.0f);
        const float var = mq * (1.0f / 256.0f) - mu * mu;
        murs[tid][0] = mu;
        murs[tid][1] = rsqrtf(var + 1e-5f);
    }
    __syncthreads();
    #pragma unroll
    for (int i = 0; i < 4; ++i)
        #pragma unroll
        for (int r = 0; r < 4; ++r) {
            const int row = i * 16 + fk * 4 + r;
            const float mu = murs[row][0], rs = murs[row][1];
            #pragma unroll
            for (int j = 0; j < 2; ++j) {
                const int col = w * 32 + j * 16 + fr;
                const float xn = (y[i][j][r] - mu) * rs * lnw[col] + lnb[col];
                x [(size_t)(bm + row) * 256 + col] = xn;
                xb[(size_t)(bm + row) * 256 + col] = f2bf(xn);
            }
        }
}

// ---------------------------------------------------------------------------
// MFMA flash attention v4. Grid (B*H); block 512 = 8 waves, 1 block/CU.
// All of K (permuted, [512][40] ushort) and V^T ([32][520]) staged to LDS
// ONCE; one barrier; then pure LDS-resident compute.
// ---------------------------------------------------------------------------
__global__ __launch_bounds__(512)
void attn_v4(const ushort* __restrict__ qk, const ushort* __restrict__ vt,
             ushort* __restrict__ out)
{
    __shared__ __align__(16) ushort Ks[512 * 40];   // 40 KB
    __shared__ __align__(16) ushort Vs[32 * 520];   // 33.3 KB
    const int bh = blockIdx.x;
    const int b = bh >> 3, h = bh & 7;
    const int tid = threadIdx.x;                    // 0..511
    const int w = tid >> 6, lane = tid & 63;
    const int g = lane >> 4, c = lane & 15;

    // stage all K (permuted within each 32-key block) and all V^T
    #pragma unroll
    for (int i = 0; i < 4; ++i) {
        const int idx = tid + i * 512;              // 0..2047
        const int kr = idx >> 2, seg = idx & 3;
        const uint4 kv = *(const uint4*)(qk + ((size_t)b * 512 + kr) * 512
                                         + 256 + h * 32 + seg * 8);
        const int p = (((kr >> 2) & 1) << 4) | (((kr >> 3) & 3) << 2) | (kr & 3);
        const int pos = (kr & ~31) | p;
        *(uint4*)&Ks[pos * 40 + seg * 8] = kv;
        const int dr = idx >> 6, vseg = idx & 63;
        const uint4 vv = *(const uint4*)(vt + (size_t)bh * 16384 + dr * 512 + vseg * 8);
        *(uint4*)&Vs[dr * 520 + vseg * 8] = vv;
    }

    // load + pre-scale this wave's 4 Q fragments (qg j -> q rows (j*8+w)*16..+15)
    bf16x8 qf[4];
    #pragma unroll
    for (int j = 0; j < 4; ++j) {
        const size_t qrow = (size_t)b * 512 + (j * 8 + w) * 16 + c;
        const uint4 qv = *(const uint4*)(qk + qrow * 512 + h * 32 + g * 8);
        float f[8]; unpack8(qv, f);
        const float scale = 0.17677669529663689f;
        union { uint u[4]; bf16x8 v; } qq;
        #pragma unroll
        for (int t = 0; t < 4; ++t) qq.u[t] = pack2(f[2*t] * scale, f[2*t+1] * scale);
        qf[j] = qq.v;
    }
    __syncthreads();

    const f32x4_t zz = {0.f, 0.f, 0.f, 0.f};
    #pragma unroll
    for (int j = 0; j < 4; ++j) {
        float m = -INFINITY, l = 0.f;
        f32x4_t o0 = zz, o1 = zz;
        for (int kt = 0; kt < 4; ++kt) {
            const int kbase = kt * 128;
            // S^T frags: 8 x mfma(K, Q)
            f32x4_t s[8];
            __builtin_amdgcn_s_setprio(1);
            #pragma unroll
            for (int kf = 0; kf < 8; ++kf) {
                const bf16x8 kfrag = *(const bf16x8*)&Ks[(kbase + kf * 16 + c) * 40 + g * 8];
                s[kf] = __builtin_amdgcn_mfma_f32_16x16x32_bf16(kfrag, qf[j], zz, 0, 0, 0);
            }
            __builtin_amdgcn_s_setprio(0);

            // online softmax (lane holds 32 keys of its q=c; reduce over g)
            float mt = s[0][0];
            #pragma unroll
            for (int kf = 0; kf < 8; ++kf)
                #pragma unroll
                for (int r = 0; r < 4; ++r) mt = fmaxf(mt, s[kf][r]);
            mt = fmaxf(mt, __shfl_xor(mt, 16));
            mt = fmaxf(mt, __shfl_xor(mt, 32));
            const float mn = fmaxf(m, mt);
            const float corr = __expf(m - mn);   // exp(-inf)=0 on first tile
            m = mn;
            float lt = 0.f;
            #pragma unroll
            for (int kf = 0; kf < 8; ++kf)
                #pragma unroll
                for (int r = 0; r < 4; ++r) {
                    const float p = __expf(s[kf][r] - mn);
                    s[kf][r] = p; lt += p;
                }
            lt += __shfl_xor(lt, 16);
            lt += __shfl_xor(lt, 32);
            l = l * corr + lt;
            #pragma unroll
            for (int r = 0; r < 4; ++r) { o0[r] *= corr; o1[r] *= corr; }

            // PV: P frags are lane-local (key permutation); O^T = V^T . P^T
            #pragma unroll
            for (int t = 0; t < 4; ++t) {
                union { uint u[4]; bf16x8 v; } pf;
                pf.u[0] = pack2(s[2*t][0],   s[2*t][1]);
                pf.u[1] = pack2(s[2*t][2],   s[2*t][3]);
                pf.u[2] = pack2(s[2*t+1][0], s[2*t+1][1]);
                pf.u[3] = pack2(s[2*t+1][2], s[2*t+1][3]);
                const bf16x8 va0 = *(const bf16x8*)&Vs[c * 520 + kbase + t * 32 + g * 8];
                const bf16x8 va1 = *(const bf16x8*)&Vs[(16 + c) * 520 + kbase + t * 32 + g * 8];
                __builtin_amdgcn_s_setprio(1);
                o0 = __builtin_amdgcn_mfma_f32_16x16x32_bf16(va0, pf.v, o0, 0, 0, 0);
                o1 = __builtin_amdgcn_mfma_f32_16x16x32_bf16(va1, pf.v, o1, 0, 0, 0);
                __builtin_amdgcn_s_setprio(0);
            }
        }

        // epilogue: O^T[d][q]: lane holds q=c, d = df*16 + g*4 + r
        const float inv = 1.0f / l;
        const size_t obase = ((size_t)b * 512 + (j * 8 + w) * 16 + c) * 256 + h * 32;
        ushort4 w0, w1;
        w0.x = f2bf(o0[0] * inv); w0.y = f2bf(o0[1] * inv);
        w0.z = f2bf(o0[2] * inv); w0.w = f2bf(o0[3] * inv);
        w1.x = f2bf(o1[0] * inv); w1.y = f2bf(o1[1] * inv);
        w1.z = f2bf(o1[2] * inv); w1.w = f2bf(o1[3] * inv);
        *(ushort4*)(out + obase + g * 4)      = w0;
        *(ushort4*)(out + obase + 16 + g * 4) = w1;
    }
}

// ---------------------------------------------------------------------------
// Final LN: xb = LN(x) (bf16 out only).
// ---------------------------------------------------------------------------
__global__ __launch_bounds__(256)
void lnf_kernel(const float* __restrict__ x, const float* __restrict__ w,
                const float* __restrict__ b, ushort* __restrict__ xb)
{
    const int lane = threadIdx.x & 63;
    const int wv = threadIdx.x >> 6;
    const size_t row = (size_t)blockIdx.x * 4 + wv;
    const float4 val = *(const float4*)(x + row * E_SZ + lane * 4);
    float s  = val.x + val.y + val.z + val.w;
    float ss = val.x * val.x + val.y * val.y + val.z * val.z + val.w * val.w;
    #pragma unroll
    for (int off = 1; off < 64; off <<= 1) {
        s  += __shfl_xor(s, off, 64);
        ss += __shfl_xor(ss, off, 64);
    }
    const float mu  = s * (1.0f / 256.0f);
    const float var = ss * (1.0f / 256.0f) - mu * mu;
    const float rs  = rsqrtf(var + 1e-5f);
    const float4 wv4 = *(const float4*)(w + lane * 4);
    const float4 bv4 = *(const float4*)(b + lane * 4);
    ushort4 ob;
    ob.x = f2bf((val.x - mu) * rs * wv4.x + bv4.x);
    ob.y = f2bf((val.y - mu) * rs * wv4.y + bv4.y);
    ob.z = f2bf((val.z - mu) * rs * wv4.z + bv4.z);
    ob.w = f2bf((val.w - mu) * rs * wv4.w + bv4.w);
    *(ushort4*)(xb + row * E_SZ + lane * 4) = ob;
}

// ---------------------------------------------------------------------------
extern "C" void kernel_launch(void* const* d_in, const int* in_sizes, int n_in,
                              void* d_out, int out_size, void* d_ws, size_t ws_size,
                              hipStream_t stream)
{
    const float* cnn   = (const float*)d_in[0];
    const float* cnn_w = (const float*)d_in[1];
    const float* cnn_b = (const float*)d_in[2];
    const float* tok   = (const float*)d_in[3];
    const float* Wq    = (const float*)d_in[4];
    const float* bq    = (const float*)d_in[5];
    const float* Wk    = (const float*)d_in[6];
    const float* bk    = (const float*)d_in[7];
    const float* Wv    = (const float*)d_in[8];
    const float* bv    = (const float*)d_in[9];
    const float* Wo    = (const float*)d_in[10];
    const float* bo    = (const float*)d_in[11];
    const float* ln1w  = (const float*)d_in[12];
    const float* ln1b  = (const float*)d_in[13];
    const float* ln2w  = (const float*)d_in[14];
    const float* ln2b  = (const float*)d_in[15];
    const float* mw1   = (const float*)d_in[16];
    const float* mb1   = (const float*)d_in[17];
    const float* mw2   = (const float*)d_in[18];
    const float* mb2   = (const float*)d_in[19];
    const float* lnfw  = (const float*)d_in[20];
    const float* lnfb  = (const float*)d_in[21];
    const float* ow1   = (const float*)d_in[22];
    const float* ob1   = (const float*)d_in[23];
    const float* ow2   = (const float*)d_in[24];
    const float* ob2   = (const float*)d_in[25];

    const int M = N_TOK;
    char* ws = (char*)d_ws;

    // Workspace layout (byte offsets in MB):
    // [0,16)  x fp32          [16,24) xb bf16       [24,40) qkb / cnnb
    // [40,48) vt bf16         [48,56) ab bf16       [40,64) hb bf16 (aliases vt+ab)
    // [64,~71) converted weights + bqkv
    float*  x     = (float*)(ws + 0);
    ushort* xb    = (ushort*)(ws + 16 * MB);
    ushort* qkb   = (ushort*)(ws + 24 * MB);
    ushort* cnnb  = (ushort*)(ws + 24 * MB);
    ushort* vt    = (ushort*)(ws + 40 * MB);
    ushort* ab_   = (ushort*)(ws + 48 * MB);
    ushort* hb_   = (ushort*)(ws + 40 * MB);
    ushort* wb    = (ushort*)(ws + 64 * MB);

    ushort* cnn_wb = wb;                    // 131072
    ushort* Wob    = wb + 131072;           // 262144
    ushort* wqkv   = wb + 393216;           // 786432 = [L][768][256]
    ushort* mw1b   = wb + 1179648;          // 786432
    ushort* mw2b   = wb + 1966080;          // 786432
    ushort* ow1b   = wb + 2752512;          // 131072
    ushort* ow2b   = wb + 2883584;          // 262144
    float*  bqkv   = (float*)(ws + 64 * MB + 6291456);   // [L][768] fp32

    // conversions (3 dispatches)
    cvt_kernel<<<dim3(4096), dim3(256), 0, stream>>>(cnn, cnnb);
    wcvt_kernel<<<dim3(1536), dim3(256), 0, stream>>>(
        cnn_w, Wo, Wq, Wk, Wv, mw1, mw2, ow1, ow2, wb);
    bqkv_kernel<<<dim3(12), dim3(256), 0, stream>>>(bq, bk, bv, bqkv);

    // x = cnn @ cnn_w^T + cnn_b + tok[0]  -> x fp32 + xb bf16
    gemm_bf16_kernel<0, 0, true, true><<<dim3(M / 128, E_SZ / 64), dim3(256), 0, stream>>>(
        cnnb, cnn_wb, cnn_b, tok, x, xb, nullptr, M, C_SZ, E_SZ);

    for (int i = 0; i < L_SZ; ++i) {
        // fused QKV: q|k -> qkb [N][512], v -> vt transposed [b][h][32][512]
        gemm_bf16_kernel<0, 1, false, false><<<dim3(M / 128, HID / 64), dim3(256), 0, stream>>>(
            xb, wqkv + (size_t)i * 196608, bqkv + (size_t)i * 768, nullptr,
            nullptr, qkb, vt, M, E_SZ, HID);

        attn_v4<<<dim3(B_SZ * H_SZ), dim3(512), 0, stream>>>(qkb, vt, ab_);

        // x = LN(x + ab @ Wo^T + bo)  (fused GEMM+add+LN)
        gemm_ln_kernel<<<dim3(M / 64), dim3(512), 0, stream>>>(
            ab_, Wob + (size_t)i * 65536, bo + (size_t)i * E_SZ,
            x, xb, ln1w + (size_t)i * E_SZ, ln1b + (size_t)i * E_SZ, E_SZ);

        // h = gelu(xb @ mw1^T + mb1) -> hb_ [N,768]
        gemm_bf16_kernel<1, 0, false, true><<<dim3(M / 128, HID / 64), dim3(256), 0, stream>>>(
            xb, mw1b + (size_t)i * HID * E_SZ, mb1 + (size_t)i * HID, nullptr,
            nullptr, hb_, nullptr, M, E_SZ, HID);

        // x = LN(x + hb @ mw2^T + mb2)  (fused GEMM+add+LN)
        gemm_ln_kernel<<<dim3(M / 64), dim3(512), 0, stream>>>(
            hb_, mw2b + (size_t)i * E_SZ * HID, mb2 + (size_t)i * E_SZ,
            x, xb, ln2w + (size_t)i * E_SZ, ln2b + (size_t)i * E_SZ, HID);
    }

    // final LN -> xb (bf16 only)
    lnf_kernel<<<dim3(M / 4), dim3(256), 0, stream>>>(x, lnfw, lnfb, xb);

    // h = gelu(xb @ ow1^T + ob1) -> hb_ [N,512]
    gemm_bf16_kernel<1, 0, false, true><<<dim3(M / 128, (2 * E_SZ) / 64), dim3(256), 0, stream>>>(
        xb, ow1b, ob1, nullptr, nullptr, hb_, nullptr, M, E_SZ, 2 * E_SZ);
    // out = relu(hb @ ow2^T + ob2) -> d_out fp32
    gemm_bf16_kernel<2, 0, true, false><<<dim3(M / 128, C_SZ / 64), dim3(256), 0, stream>>>(
        hb_, ow2b, ob2, nullptr, (float*)d_out, nullptr, nullptr, M, 2 * E_SZ, C_SZ);
}